// Round 2
// baseline (752.136 us; speedup 1.0000x reference)
//
#include <hip/hip_runtime.h>
#include <stdint.h>

// ============================================================================
// HyperPatch: reproduce jax.random.categorical sampling bit-exactly, then
// gather 3x3x3 patches at the sampled centers.
//
// RNG model: JAX threefry2x32 with jax_threefry_partitionable semantics
// (default True since JAX 0.4.36):
//   - random_bits(key, 32, shape): per-element counter (hi=0, lo=i),
//     bits = x0_out ^ x1_out
//   - split(key, 4) [foldlike]: counter (0, i); keys[i] = (x0_out, x1_out)
//     -- RAW pair, NO xor fold (this was round-1's bug).
// Fallback (PARTITIONABLE=0): original pair-halved iota scheme.
//
// Argmax trick: all nonzero probs are exactly 1.0 -> logits are exactly 0.0 or
// -inf; gumbel(-log(-log(u))) is monotone in u which is monotone in (bits>>9).
// So categorical = argmax over allowed s of (bits>>9), tie -> lowest flat
// index. Encoded as u64 key ((val23+1)<<18) | (S-1-s); integer max.
// ============================================================================

#define PARTITIONABLE 1

#define S_VOL 262144      // 64*64*64
#define OUT_N 221184      // 2*8*1*2*32*8*27

struct Keys { uint32_t k[4][2]; };

#define TF_ROUND(r) { x0 += x1; x1 = (x1 << (r)) | (x1 >> (32 - (r))); x1 ^= x0; }

__host__ __device__ static inline void tf2x32(uint32_t k0, uint32_t k1,
                                              uint32_t& x0, uint32_t& x1) {
  uint32_t ks2 = k0 ^ k1 ^ 0x1BD11BDAu;
  x0 += k0; x1 += k1;
  TF_ROUND(13) TF_ROUND(15) TF_ROUND(26) TF_ROUND(6)
  x0 += k1;  x1 += ks2 + 1u;
  TF_ROUND(17) TF_ROUND(29) TF_ROUND(16) TF_ROUND(24)
  x0 += ks2; x1 += k0 + 2u;
  TF_ROUND(13) TF_ROUND(15) TF_ROUND(26) TF_ROUND(6)
  x0 += k0;  x1 += k1 + 3u;
  TF_ROUND(17) TF_ROUND(29) TF_ROUND(16) TF_ROUND(24)
  x0 += k1;  x1 += ks2 + 4u;
  TF_ROUND(13) TF_ROUND(15) TF_ROUND(26) TF_ROUND(6)
  x0 += ks2; x1 += k0 + 5u;
}

// ---------------------------------------------------------------------------
// Kernel 1: per-voxel flags + per-batch indicator sums.
// flag bits: 0=pos(mask==1) 1=neg 2=pos_boundary 3=neg_boundary 4=interior
// ---------------------------------------------------------------------------
__global__ __launch_bounds__(256) void k_flags(const int* __restrict__ mask,
                                               uint8_t* __restrict__ flags,
                                               int* __restrict__ sums) {
  int t = blockIdx.x * 256 + threadIdx.x;           // [0, 2*S_VOL)
  int b = t >> 18;
  int s = t & (S_VOL - 1);
  int z = s >> 12, y = (s >> 6) & 63, x = s & 63;
  int m = mask[t];
  int cnt = 0;
  #pragma unroll
  for (int dz = -1; dz <= 1; ++dz) {
    int zz = z + dz; if (zz < 0 || zz > 63) continue;
    #pragma unroll
    for (int dy = -1; dy <= 1; ++dy) {
      int yy = y + dy; if (yy < 0 || yy > 63) continue;
      #pragma unroll
      for (int dx = -1; dx <= 1; ++dx) {
        int xx = x + dx; if (xx < 0 || xx > 63) continue;
        cnt += mask[(b << 18) + (zz << 12) + (yy << 6) + xx];
      }
    }
  }
  int pos  = (m == 1);
  int neg  = (m == 0);
  int posb = pos && (cnt < 27);
  int negb = neg && (cnt > 0);
  int intr = (z >= 1 && z <= 62 && y >= 1 && y <= 62 && x >= 1 && x <= 62);
  flags[t] = (uint8_t)(pos | (neg << 1) | (posb << 2) | (negb << 3) | (intr << 4));

  __shared__ int ss[4];
  if (threadIdx.x < 4) ss[threadIdx.x] = 0;
  __syncthreads();
  int lane = threadIdx.x & 63;
  unsigned long long bv;
  bv = __ballot(pos);  if (lane == 0) atomicAdd(&ss[0], (int)__popcll(bv));
  bv = __ballot(neg);  if (lane == 0) atomicAdd(&ss[1], (int)__popcll(bv));
  bv = __ballot(posb); if (lane == 0) atomicAdd(&ss[2], (int)__popcll(bv));
  bv = __ballot(negb); if (lane == 0) atomicAdd(&ss[3], (int)__popcll(bv));
  __syncthreads();
  if (threadIdx.x < 4) atomicAdd(&sums[b * 4 + threadIdx.x], ss[threadIdx.x]);
}

// selection of which flag bit gates the categorical, per (call, batch)
__device__ static inline void get_sel(int c, int b, const int* __restrict__ sums,
                                      uint32_t& bitmask, bool& allowall) {
  int sp, sf, pb, fbb;
  switch (c) {
    case 0:  sp = sums[b*4+2]; sf = sums[b*4+0]; pb = 2; fbb = 0; break;  // pos_b, fb pos
    case 1:  sp = sums[b*4+0]; sf = 1;           pb = 0; fbb = 4; break;  // pos,   fb valid
    case 2:  sp = sums[b*4+3]; sf = sums[b*4+1]; pb = 3; fbb = 1; break;  // neg_b, fb neg
    default: sp = sums[b*4+1]; sf = 1;           pb = 1; fbb = 4; break;  // neg,   fb valid
  }
  allowall = false;
  if (sp > 0)      bitmask = 1u << pb;
  else if (sf > 0) bitmask = 1u << fbb;
  else { allowall = true; bitmask = 0; }
}

__device__ static inline unsigned long long shfl_down_u64(unsigned long long v, int off) {
  uint32_t lo = (uint32_t)v, hi = (uint32_t)(v >> 32);
  lo = __shfl_down(lo, off);
  hi = __shfl_down(hi, off);
  return ((unsigned long long)hi << 32) | lo;
}

__device__ __constant__ const int c_sbase[4] = {0, 352, 512, 864};

// ---------------------------------------------------------------------------
// Kernel 2A (PARTITIONABLE): one wg per (call, draw j, row n, S-chunk).
// Layout: c0: 22*16*4=1408, c1: 10*16*4=640, c2: 1408, c3: 640  -> 4096 wgs.
// Gumbel flat index i = (j*16 + n)*S + s; counter = (0, i); bits = x0^x1.
// ---------------------------------------------------------------------------
__global__ __launch_bounds__(256) void k_sample_part(const uint8_t* __restrict__ flags,
                                                     const int* __restrict__ sums,
                                                     unsigned long long* __restrict__ slots,
                                                     Keys keys) {
  int wg = blockIdx.x;
  int c, rem;
  if      (wg < 1408) { c = 0; rem = wg; }
  else if (wg < 2048) { c = 1; rem = wg - 1408; }
  else if (wg < 3456) { c = 2; rem = wg - 2048; }
  else                { c = 3; rem = wg - 3456; }
  int chunk = rem & 3;
  int n     = (rem >> 2) & 15;
  int j     = rem >> 6;
  int b     = n >> 3;

  uint32_t bitmask; bool allowall;
  get_sel(c, b, sums, bitmask, allowall);

  uint32_t k0 = keys.k[c][0], k1 = keys.k[c][1];
  uint32_t ibase = (uint32_t)(j * 16 + n) * (uint32_t)S_VOL;
  const uint8_t* fbp = flags + b * S_VOL;

  unsigned long long best = 0ull;
  int s0 = (chunk << 16) + threadIdx.x;
  for (int it = 0; it < 256; ++it) {
    int s = s0 + (it << 8);
    uint32_t ok = allowall ? 1u : (uint32_t)(fbp[s] & bitmask);
    uint32_t x0 = 0u, x1 = ibase + (uint32_t)s;
    tf2x32(k0, k1, x0, x1);
    uint32_t bits = x0 ^ x1;
    unsigned long long cand =
        ok ? ((((unsigned long long)((bits >> 9) + 1u)) << 18)
              | (unsigned long long)(S_VOL - 1 - s))
           : 0ull;
    best = best > cand ? best : cand;
  }
  #pragma unroll
  for (int off = 32; off; off >>= 1) {
    unsigned long long o = shfl_down_u64(best, off);
    best = best > o ? best : o;
  }
  if ((threadIdx.x & 63) == 0)
    atomicMax(&slots[c_sbase[c] + j * 16 + n], best);
}

// ---------------------------------------------------------------------------
// Kernel 2B (original, pre-0.4.36): pair-halved iota. One wg per
// (call, jlo, n, chunk); pair (i, i+half) yields draws jlo and jlo+k/2.
// Layout: c0: 11*16*4=704, c1: 5*16*4=320, c2: 704, c3: 320 -> 2048 wgs.
// ---------------------------------------------------------------------------
__global__ __launch_bounds__(256) void k_sample_orig(const uint8_t* __restrict__ flags,
                                                     const int* __restrict__ sums,
                                                     unsigned long long* __restrict__ slots,
                                                     Keys keys) {
  int wg = blockIdx.x;
  int c, rem;
  if      (wg < 704)  { c = 0; rem = wg; }
  else if (wg < 1024) { c = 1; rem = wg - 704; }
  else if (wg < 1728) { c = 2; rem = wg - 1024; }
  else                { c = 3; rem = wg - 1728; }
  const int rkh[4] = {11, 5, 11, 5};
  int chunk = rem & 3;
  int n     = (rem >> 2) & 15;
  int jlo   = rem >> 6;
  int b     = n >> 3;
  int halfj = rkh[c];
  uint32_t half_count = (uint32_t)halfj * 16u * (uint32_t)S_VOL;

  uint32_t bitmask; bool allowall;
  get_sel(c, b, sums, bitmask, allowall);

  uint32_t k0 = keys.k[c][0], k1 = keys.k[c][1];
  uint32_t ibase = (uint32_t)(jlo * 16 + n) * (uint32_t)S_VOL;
  const uint8_t* fbp = flags + b * S_VOL;

  unsigned long long best0 = 0ull, best1 = 0ull;
  int s0 = (chunk << 16) + threadIdx.x;
  for (int it = 0; it < 256; ++it) {
    int s = s0 + (it << 8);
    uint32_t ok = allowall ? 1u : (uint32_t)(fbp[s] & bitmask);
    uint32_t x0 = ibase + (uint32_t)s;
    uint32_t x1 = x0 + half_count;
    tf2x32(k0, k1, x0, x1);
    unsigned long long tb = (unsigned long long)(S_VOL - 1 - s);
    unsigned long long c0v = ok ? ((((unsigned long long)((x0 >> 9) + 1u)) << 18) | tb) : 0ull;
    unsigned long long c1v = ok ? ((((unsigned long long)((x1 >> 9) + 1u)) << 18) | tb) : 0ull;
    best0 = best0 > c0v ? best0 : c0v;
    best1 = best1 > c1v ? best1 : c1v;
  }
  #pragma unroll
  for (int off = 32; off; off >>= 1) {
    unsigned long long o0 = shfl_down_u64(best0, off);
    unsigned long long o1 = shfl_down_u64(best1, off);
    best0 = best0 > o0 ? best0 : o0;
    best1 = best1 > o1 ? best1 : o1;
  }
  if ((threadIdx.x & 63) == 0) {
    atomicMax(&slots[c_sbase[c] + jlo * 16 + n], best0);
    atomicMax(&slots[c_sbase[c] + (jlo + halfj) * 16 + n], best1);
  }
}

// ---------------------------------------------------------------------------
// Kernel 3: gather 3x3x3 patches (replicate pad == clamp) into output layout
// (B, G, R=1, [t=pos/neg][m][cg][o]).
// ---------------------------------------------------------------------------
__global__ __launch_bounds__(256) void k_gather(const float* __restrict__ fmap,
                                                const unsigned long long* __restrict__ slots,
                                                float* __restrict__ out) {
  int tid = blockIdx.x * 256 + threadIdx.x;
  if (tid >= OUT_N) return;
  int o  = tid % 27;
  int q  = tid / 27;
  int cg = q & 7;   q >>= 3;
  int m  = q & 31;  q >>= 5;
  int t  = q & 1;   q >>= 1;
  int gi = q & 7;
  int b  = q >> 3;
  int n  = b * 8 + gi;
  int slot;
  if (t == 0) slot = (m < 22) ? (m * 16 + n) : (352 + (m - 22) * 16 + n);
  else        slot = (m < 22) ? (512 + m * 16 + n) : (864 + (m - 22) * 16 + n);
  int s = (S_VOL - 1) - (int)(slots[slot] & 0x3FFFFull);
  int z = s >> 12, y = (s >> 6) & 63, x = s & 63;
  int dz = o / 9 - 1, dy = (o / 3) % 3 - 1, dx = o % 3 - 1;
  int zc = min(max(z + dz, 0), 63);
  int yc = min(max(y + dy, 0), 63);
  int xc = min(max(x + dx, 0), 63);
  int ch = gi * 8 + cg;
  out[tid] = fmap[((b * 64 + ch) << 18) + (zc << 12) + (yc << 6) + xc];
}

// ---------------------------------------------------------------------------
extern "C" void kernel_launch(void* const* d_in, const int* in_sizes, int n_in,
                              void* d_out, int out_size, void* d_ws, size_t ws_size,
                              hipStream_t stream) {
  const float* fmap = (const float*)d_in[0];
  const int*   mask = (const int*)d_in[1];
  float* out = (float*)d_out;
  // flags scratch lives in d_out (first 512KB); gather fully overwrites later.
  uint8_t* flags = (uint8_t*)d_out;
  int* sums = (int*)d_ws;
  unsigned long long* slots = (unsigned long long*)((char*)d_ws + 64);

  // host-side: keys = jax.random.split(jax.random.key(42), 4)
  Keys K;
#if PARTITIONABLE
  // foldlike split: counter (0, i); keys[i] = RAW (x0_out, x1_out) -- no xor.
  for (int c = 0; c < 4; ++c) {
    uint32_t x0 = 0u, x1 = (uint32_t)c;
    tf2x32(0u, 42u, x0, x1);
    K.k[c][0] = x0; K.k[c][1] = x1;
  }
#else
  uint32_t a[4], bb[4];
  for (int i = 0; i < 4; ++i) {
    uint32_t x0 = (uint32_t)i, x1 = (uint32_t)(i + 4);
    tf2x32(0u, 42u, x0, x1);
    a[i] = x0; bb[i] = x1;
  }
  K.k[0][0] = a[0];  K.k[0][1] = a[1];
  K.k[1][0] = a[2];  K.k[1][1] = a[3];
  K.k[2][0] = bb[0]; K.k[2][1] = bb[1];
  K.k[3][0] = bb[2]; K.k[3][1] = bb[3];
#endif

  hipMemsetAsync(d_ws, 0, 64 + 1024 * 8, stream);
  hipLaunchKernelGGL(k_flags, dim3(2048), dim3(256), 0, stream, mask, flags, sums);
#if PARTITIONABLE
  hipLaunchKernelGGL(k_sample_part, dim3(4096), dim3(256), 0, stream, flags, sums, slots, K);
#else
  hipLaunchKernelGGL(k_sample_orig, dim3(2048), dim3(256), 0, stream, flags, sums, slots, K);
#endif
  hipLaunchKernelGGL(k_gather, dim3((OUT_N + 255) / 256), dim3(256), 0, stream, fmap, slots, out);
}

// Round 3
// 654.589 us; speedup vs baseline: 1.1490x; 1.1490x over previous
//
#include <hip/hip_runtime.h>
#include <stdint.h>

// ============================================================================
// HyperPatch: bit-exact jax.random.categorical (threefry2x32, partitionable)
// + 3x3x3 patch gather.
//
// categorical with 0/1 probs == argmax over allowed s of (threefry_bits>>9),
// tie -> lowest flat index. Encoded u64 key ((val23+1)<<18)|(S-1-s); max.
//
// Round-2 optimization: stream-compact allowed index lists per (batch, set)
// so the sampler hashes only allowed positions (~2x fewer hashes) with a
// hand-tightened threefry loop (alignbit rotates, uint4 list loads, x4 unroll).
// ============================================================================

#define S_VOL   262144          // 64*64*64
#define VALID_N 238328          // 62^3
#define OUT_N   221184          // 2*8*1*2*32*8*27

struct Keys { uint32_t k[4][2]; };

// ---------------- threefry2x32 ----------------
#define TF_ROUND(r) { x0 += x1; x1 = (x1 << (r)) | (x1 >> (32 - (r))); x1 ^= x0; }

__host__ __device__ static inline void tf2x32(uint32_t k0, uint32_t k1,
                                              uint32_t& x0, uint32_t& x1) {
  uint32_t ks2 = k0 ^ k1 ^ 0x1BD11BDAu;
  x0 += k0; x1 += k1;
  TF_ROUND(13) TF_ROUND(15) TF_ROUND(26) TF_ROUND(6)
  x0 += k1;  x1 += ks2 + 1u;
  TF_ROUND(17) TF_ROUND(29) TF_ROUND(16) TF_ROUND(24)
  x0 += ks2; x1 += k0 + 2u;
  TF_ROUND(13) TF_ROUND(15) TF_ROUND(26) TF_ROUND(6)
  x0 += k0;  x1 += k1 + 3u;
  TF_ROUND(17) TF_ROUND(29) TF_ROUND(16) TF_ROUND(24)
  x0 += k1;  x1 += ks2 + 4u;
  TF_ROUND(13) TF_ROUND(15) TF_ROUND(26) TF_ROUND(6)
  x0 += ks2; x1 += k0 + 5u;
}

// device-side tight hash: x0 starts at k0, x1 at (s + ibase + k1); key-schedule
// constants pre-added by caller. Rotates forced to v_alignbit_b32.
#define ROTL(x, r) __builtin_amdgcn_alignbit((x), (x), 32u - (r))
#define R4(a,b,c,d) { x0+=x1; x1=ROTL(x1,a); x1^=x0; \
                      x0+=x1; x1=ROTL(x1,b); x1^=x0; \
                      x0+=x1; x1=ROTL(x1,c); x1^=x0; \
                      x0+=x1; x1=ROTL(x1,d); x1^=x0; }

struct TFC { uint32_t x0i, sk1, a1,b1,a2,b2,a3,b3,a4,b4,a5,b5; };

__device__ static inline uint32_t tf_hash(uint32_t s, const TFC& c) {
  uint32_t x0 = c.x0i, x1 = s + c.sk1;
  R4(13,15,26,6)   x0 += c.a1; x1 += c.b1;
  R4(17,29,16,24)  x0 += c.a2; x1 += c.b2;
  R4(13,15,26,6)   x0 += c.a3; x1 += c.b3;
  R4(17,29,16,24)  x0 += c.a4; x1 += c.b4;
  R4(13,15,26,6)   x0 += c.a5; x1 += c.b5;
  return x0 ^ x1;
}

__device__ static inline unsigned long long shfl_down_u64(unsigned long long v, int off) {
  uint32_t lo = (uint32_t)v, hi = (uint32_t)(v >> 32);
  lo = __shfl_down(lo, off);
  hi = __shfl_down(hi, off);
  return ((unsigned long long)hi << 32) | lo;
}

// ===========================================================================
// FAST PATH
// ws layout: ctr int[8] @0 (set: 0=posb 1=pos 2=negb 3=neg, per b)
//            slots u64[1024] @128
//            lists u32[4*S_VOL] @16384:
//              regA(b)=lists+b*2S: posb front, negb back (posb+negb<=S)
//              regB(b)=regA+S:     pos  front, neg  back (pos+neg==S)
// ===========================================================================

__device__ static inline void emit_one(bool pred, int* c, uint32_t* reg,
                                       bool back, int s, int lane) {
  unsigned long long bv = __ballot(pred);
  int cnt = (int)__popcll(bv);
  int base = 0;
  if (lane == 0 && cnt) base = atomicAdd(c, cnt);
  base = __shfl(base, 0);
  if (pred) {
    int idx = base + (int)__popcll(bv & ((1ull << lane) - 1ull));
    reg[back ? (S_VOL - 1 - idx) : idx] = (uint32_t)s;
  }
}

__global__ __launch_bounds__(256) void k_compact(const int* __restrict__ mask,
                                                 int* __restrict__ ctr,
                                                 uint32_t* __restrict__ lists) {
  int t = blockIdx.x * 256 + threadIdx.x;           // [0, 2*S_VOL)
  int b = t >> 18;
  int s = t & (S_VOL - 1);
  int z = s >> 12, y = (s >> 6) & 63, x = s & 63;
  int m = mask[t];
  int cnt = 0;
  #pragma unroll
  for (int dz = -1; dz <= 1; ++dz) {
    int zz = z + dz; if (zz < 0 || zz > 63) continue;
    #pragma unroll
    for (int dy = -1; dy <= 1; ++dy) {
      int yy = y + dy; if (yy < 0 || yy > 63) continue;
      #pragma unroll
      for (int dx = -1; dx <= 1; ++dx) {
        int xx = x + dx; if (xx < 0 || xx > 63) continue;
        cnt += mask[(b << 18) + (zz << 12) + (yy << 6) + xx];
      }
    }
  }
  bool pos  = (m == 1);
  bool neg  = (m == 0);
  bool posb = pos && (cnt < 27);
  bool negb = neg && (cnt > 0);
  uint32_t* regA = lists + (size_t)b * (2 * S_VOL);
  uint32_t* regB = regA + S_VOL;
  int lane = threadIdx.x & 63;
  emit_one(posb, &ctr[b * 4 + 0], regA, false, s, lane);
  emit_one(pos,  &ctr[b * 4 + 1], regB, false, s, lane);
  emit_one(negb, &ctr[b * 4 + 2], regA, true,  s, lane);
  emit_one(neg,  &ctr[b * 4 + 3], regB, true,  s, lane);
}

// pad lists to uint4 alignment with duplicate entries (dups can't change max)
__global__ void k_pad(const int* __restrict__ ctr, uint32_t* __restrict__ lists) {
  int i = threadIdx.x;
  if (i >= 8) return;
  int b = i >> 2, set = i & 3;
  uint32_t* regA = lists + (size_t)b * (2 * S_VOL);
  uint32_t* reg = (set == 1 || set == 3) ? regA + S_VOL : regA;
  int cnt = ctr[b * 4 + set];
  if (cnt == 0 || cnt == S_VOL) return;
  if (set < 2) {                 // front list: pad tail [cnt, roundup4)
    uint32_t v = reg[0];
    for (int q = cnt; q < ((cnt + 3) & ~3); ++q) reg[q] = v;
  } else {                       // back list: pad head [(S-cnt)&~3, S-cnt)
    int st = S_VOL - cnt;
    uint32_t v = reg[st];
    for (int q = (st & ~3); q < st; ++q) reg[q] = v;
  }
}

// one wg per (slot d, chunk); 2048 wgs total
__global__ __launch_bounds__(256) void k_sample_list(const int* __restrict__ ctr,
                                                     const uint32_t* __restrict__ lists,
                                                     unsigned long long* __restrict__ slots,
                                                     Keys keys) {
  int wg = blockIdx.x;
  int chunk = wg & 1;
  int d = wg >> 1;                       // slot id in [0,1024)
  int c, rem;
  if      (d < 352) { c = 0; rem = d; }
  else if (d < 512) { c = 1; rem = d - 352; }
  else if (d < 864) { c = 2; rem = d - 512; }
  else              { c = 3; rem = d - 864; }
  int n = rem & 15, j = rem >> 4;
  int b = n >> 3;

  // mode: 0=list, 2=valid-arith, 3=all-arith
  int mode = 0, set = 0;
  if (c == 0)      { if (ctr[b*4+0]) set = 0; else if (ctr[b*4+1]) set = 1; else mode = 3; }
  else if (c == 1) { if (ctr[b*4+1]) set = 1; else mode = 2; }
  else if (c == 2) { if (ctr[b*4+2]) set = 2; else if (ctr[b*4+3]) set = 3; else mode = 3; }
  else             { if (ctr[b*4+3]) set = 3; else mode = 2; }

  // threefry constants
  uint32_t k0 = keys.k[c][0], k1 = keys.k[c][1];
  uint32_t ks2 = k0 ^ k1 ^ 0x1BD11BDAu;
  uint32_t ibase = (uint32_t)(j * 16 + n) * (uint32_t)S_VOL;
  TFC tc;
  tc.x0i = k0; tc.sk1 = ibase + k1;
  tc.a1 = k1;  tc.b1 = ks2 + 1u;
  tc.a2 = ks2; tc.b2 = k0 + 2u;
  tc.a3 = k0;  tc.b3 = k1 + 3u;
  tc.a4 = k1;  tc.b4 = ks2 + 4u;
  tc.a5 = ks2; tc.b5 = k0 + 5u;

  int tid = threadIdx.x;
  unsigned long long best = 0ull;

  if (mode == 0) {
    const uint32_t* regA = lists + (size_t)b * (2 * S_VOL);
    const uint32_t* reg = (set == 1 || set == 3) ? regA + S_VOL : regA;
    int cnt = ctr[b * 4 + set];
    const uint32_t* base;
    int len4;
    if (set < 2) { base = reg; len4 = (cnt + 3) >> 2; }
    else { int st = (S_VOL - cnt) & ~3; base = reg + st; len4 = (S_VOL - st) >> 2; }
    const uint4* p4 = (const uint4*)base;
    for (uint32_t gi = (uint32_t)chunk; gi * 256u < (uint32_t)len4; gi += 2u) {
      uint32_t qi = gi * 256u + (uint32_t)tid;
      if (qi < (uint32_t)len4) {
        uint4 sv = p4[qi];
        #pragma unroll
        for (int u = 0; u < 4; ++u) {
          uint32_t s = (u == 0) ? sv.x : (u == 1) ? sv.y : (u == 2) ? sv.z : sv.w;
          uint32_t bits = tf_hash(s, tc);
          uint32_t vp = (bits >> 9) + 1u;
          unsigned long long key =
              ((unsigned long long)vp << 18) | (unsigned long long)((S_VOL - 1u) - s);
          best = best > key ? best : key;
        }
      }
    }
  } else if (mode == 2) {
    for (uint32_t i = (uint32_t)(chunk * 256 + tid); i < VALID_N; i += 512u) {
      uint32_t z = i / 3844u;
      uint32_t r2 = i - z * 3844u;
      uint32_t y = r2 / 62u;
      uint32_t x = r2 - y * 62u;
      uint32_t s = ((z + 1u) << 12) | ((y + 1u) << 6) | (x + 1u);
      uint32_t bits = tf_hash(s, tc);
      uint32_t vp = (bits >> 9) + 1u;
      unsigned long long key =
          ((unsigned long long)vp << 18) | (unsigned long long)((S_VOL - 1u) - s);
      best = best > key ? best : key;
    }
  } else {
    for (uint32_t s = (uint32_t)(chunk * 256 + tid); s < S_VOL; s += 512u) {
      uint32_t bits = tf_hash(s, tc);
      uint32_t vp = (bits >> 9) + 1u;
      unsigned long long key =
          ((unsigned long long)vp << 18) | (unsigned long long)((S_VOL - 1u) - s);
      best = best > key ? best : key;
    }
  }

  #pragma unroll
  for (int off = 32; off; off >>= 1) {
    unsigned long long o = shfl_down_u64(best, off);
    best = best > o ? best : o;
  }
  if ((tid & 63) == 0) atomicMax(&slots[d], best);
}

// ===========================================================================
// SLOW (fallback) PATH — round-2 passing pipeline, used if ws too small
// ===========================================================================
__global__ __launch_bounds__(256) void k_flags(const int* __restrict__ mask,
                                               uint8_t* __restrict__ flags,
                                               int* __restrict__ sums) {
  int t = blockIdx.x * 256 + threadIdx.x;
  int b = t >> 18;
  int s = t & (S_VOL - 1);
  int z = s >> 12, y = (s >> 6) & 63, x = s & 63;
  int m = mask[t];
  int cnt = 0;
  #pragma unroll
  for (int dz = -1; dz <= 1; ++dz) {
    int zz = z + dz; if (zz < 0 || zz > 63) continue;
    #pragma unroll
    for (int dy = -1; dy <= 1; ++dy) {
      int yy = y + dy; if (yy < 0 || yy > 63) continue;
      #pragma unroll
      for (int dx = -1; dx <= 1; ++dx) {
        int xx = x + dx; if (xx < 0 || xx > 63) continue;
        cnt += mask[(b << 18) + (zz << 12) + (yy << 6) + xx];
      }
    }
  }
  int pos  = (m == 1);
  int neg  = (m == 0);
  int posb = pos && (cnt < 27);
  int negb = neg && (cnt > 0);
  int intr = (z >= 1 && z <= 62 && y >= 1 && y <= 62 && x >= 1 && x <= 62);
  flags[t] = (uint8_t)(pos | (neg << 1) | (posb << 2) | (negb << 3) | (intr << 4));
  __shared__ int ss[4];
  if (threadIdx.x < 4) ss[threadIdx.x] = 0;
  __syncthreads();
  int lane = threadIdx.x & 63;
  unsigned long long bv;
  bv = __ballot(pos);  if (lane == 0) atomicAdd(&ss[0], (int)__popcll(bv));
  bv = __ballot(neg);  if (lane == 0) atomicAdd(&ss[1], (int)__popcll(bv));
  bv = __ballot(posb); if (lane == 0) atomicAdd(&ss[2], (int)__popcll(bv));
  bv = __ballot(negb); if (lane == 0) atomicAdd(&ss[3], (int)__popcll(bv));
  __syncthreads();
  if (threadIdx.x < 4) atomicAdd(&sums[b * 4 + threadIdx.x], ss[threadIdx.x]);
}

__device__ static inline void get_sel(int c, int b, const int* __restrict__ sums,
                                      uint32_t& bitmask, bool& allowall) {
  int sp, sf, pb, fbb;
  switch (c) {
    case 0:  sp = sums[b*4+2]; sf = sums[b*4+0]; pb = 2; fbb = 0; break;
    case 1:  sp = sums[b*4+0]; sf = 1;           pb = 0; fbb = 4; break;
    case 2:  sp = sums[b*4+3]; sf = sums[b*4+1]; pb = 3; fbb = 1; break;
    default: sp = sums[b*4+1]; sf = 1;           pb = 1; fbb = 4; break;
  }
  allowall = false;
  if (sp > 0)      bitmask = 1u << pb;
  else if (sf > 0) bitmask = 1u << fbb;
  else { allowall = true; bitmask = 0; }
}

__device__ __constant__ const int c_sbase[4] = {0, 352, 512, 864};

__global__ __launch_bounds__(256) void k_sample_part(const uint8_t* __restrict__ flags,
                                                     const int* __restrict__ sums,
                                                     unsigned long long* __restrict__ slots,
                                                     Keys keys) {
  int wg = blockIdx.x;
  int c, rem;
  if      (wg < 1408) { c = 0; rem = wg; }
  else if (wg < 2048) { c = 1; rem = wg - 1408; }
  else if (wg < 3456) { c = 2; rem = wg - 2048; }
  else                { c = 3; rem = wg - 3456; }
  int chunk = rem & 3;
  int n     = (rem >> 2) & 15;
  int j     = rem >> 6;
  int b     = n >> 3;
  uint32_t bitmask; bool allowall;
  get_sel(c, b, sums, bitmask, allowall);
  uint32_t k0 = keys.k[c][0], k1 = keys.k[c][1];
  uint32_t ibase = (uint32_t)(j * 16 + n) * (uint32_t)S_VOL;
  const uint8_t* fbp = flags + b * S_VOL;
  unsigned long long best = 0ull;
  int s0 = (chunk << 16) + threadIdx.x;
  for (int it = 0; it < 256; ++it) {
    int s = s0 + (it << 8);
    uint32_t ok = allowall ? 1u : (uint32_t)(fbp[s] & bitmask);
    uint32_t x0 = 0u, x1 = ibase + (uint32_t)s;
    tf2x32(k0, k1, x0, x1);
    uint32_t bits = x0 ^ x1;
    unsigned long long cand =
        ok ? ((((unsigned long long)((bits >> 9) + 1u)) << 18)
              | (unsigned long long)(S_VOL - 1 - s))
           : 0ull;
    best = best > cand ? best : cand;
  }
  #pragma unroll
  for (int off = 32; off; off >>= 1) {
    unsigned long long o = shfl_down_u64(best, off);
    best = best > o ? best : o;
  }
  if ((threadIdx.x & 63) == 0)
    atomicMax(&slots[c_sbase[c] + j * 16 + n], best);
}

// ===========================================================================
// Gather (shared by both paths)
// ===========================================================================
__global__ __launch_bounds__(256) void k_gather(const float* __restrict__ fmap,
                                                const unsigned long long* __restrict__ slots,
                                                float* __restrict__ out) {
  int tid = blockIdx.x * 256 + threadIdx.x;
  if (tid >= OUT_N) return;
  int o  = tid % 27;
  int q  = tid / 27;
  int cg = q & 7;   q >>= 3;
  int m  = q & 31;  q >>= 5;
  int t  = q & 1;   q >>= 1;
  int gi = q & 7;
  int b  = q >> 3;
  int n  = b * 8 + gi;
  int slot;
  if (t == 0) slot = (m < 22) ? (m * 16 + n) : (352 + (m - 22) * 16 + n);
  else        slot = (m < 22) ? (512 + m * 16 + n) : (864 + (m - 22) * 16 + n);
  int s = (S_VOL - 1) - (int)(slots[slot] & 0x3FFFFull);
  int z = s >> 12, y = (s >> 6) & 63, x = s & 63;
  int dz = o / 9 - 1, dy = (o / 3) % 3 - 1, dx = o % 3 - 1;
  int zc = min(max(z + dz, 0), 63);
  int yc = min(max(y + dy, 0), 63);
  int xc = min(max(x + dx, 0), 63);
  int ch = gi * 8 + cg;
  out[tid] = fmap[((b * 64 + ch) << 18) + (zc << 12) + (yc << 6) + xc];
}

// ===========================================================================
extern "C" void kernel_launch(void* const* d_in, const int* in_sizes, int n_in,
                              void* d_out, int out_size, void* d_ws, size_t ws_size,
                              hipStream_t stream) {
  const float* fmap = (const float*)d_in[0];
  const int*   mask = (const int*)d_in[1];
  float* out = (float*)d_out;

  int* ctr = (int*)d_ws;                                              // 8 ints
  unsigned long long* slots = (unsigned long long*)((char*)d_ws + 128);  // 1024 u64
  uint32_t* lists = (uint32_t*)((char*)d_ws + 16384);                 // 4*S u32

  // keys = jax.random.split(jax.random.key(42), 4): foldlike, RAW pair output
  Keys K;
  for (int c = 0; c < 4; ++c) {
    uint32_t x0 = 0u, x1 = (uint32_t)c;
    tf2x32(0u, 42u, x0, x1);
    K.k[c][0] = x0; K.k[c][1] = x1;
  }

  size_t need = 16384ull + 4ull * S_VOL * 4ull;
  hipMemsetAsync(d_ws, 0, 16384, stream);
  if (ws_size >= need) {
    hipLaunchKernelGGL(k_compact, dim3(2048), dim3(256), 0, stream, mask, ctr, lists);
    hipLaunchKernelGGL(k_pad, dim3(1), dim3(64), 0, stream, ctr, lists);
    hipLaunchKernelGGL(k_sample_list, dim3(2048), dim3(256), 0, stream, ctr, lists, slots, K);
  } else {
    uint8_t* flags = (uint8_t*)d_out;   // scratch; overwritten by gather
    hipLaunchKernelGGL(k_flags, dim3(2048), dim3(256), 0, stream, mask, flags, ctr);
    hipLaunchKernelGGL(k_sample_part, dim3(4096), dim3(256), 0, stream, flags, ctr, slots, K);
  }
  hipLaunchKernelGGL(k_gather, dim3((OUT_N + 255) / 256), dim3(256), 0, stream, fmap, slots, out);
}

// Round 4
// 305.448 us; speedup vs baseline: 2.4624x; 2.1430x over previous
//
#include <hip/hip_runtime.h>
#include <stdint.h>

// ============================================================================
// HyperPatch: bit-exact jax.random.categorical (threefry2x32, partitionable)
// + 3x3x3 patch gather.
//
// categorical with 0/1 probs == argmax over allowed s of (threefry_bits>>9),
// tie -> lowest flat index. Encoded u64 key ((val23+1)<<18)|(S-1-s); max.
//
// Round-3: k_compact was atomic-serialization-bound (32K same-line atomics,
// VALUBusy 0.8%). Now: per-block LDS aggregation -> 1 atomic per (block,set),
// counters padded to separate 64B lines.
//
// ws layout: ctr   @0      int, stride 16 u32 (64B/counter), 8 counters
//            slots @1024   u64[1024]
//            lists @16384  u32[4*S_VOL]:
//              regA(b)=lists+b*2S: posb front, negb back
//              regB(b)=regA+S:     pos  front, neg  back
// ============================================================================

#define S_VOL   262144          // 64*64*64
#define VALID_N 238328          // 62^3
#define OUT_N   221184          // 2*8*1*2*32*8*27
#define CTR(b, set) (((b) * 4 + (set)) * 16)

struct Keys { uint32_t k[4][2]; };

// ---------------- threefry2x32 ----------------
#define TF_ROUND(r) { x0 += x1; x1 = (x1 << (r)) | (x1 >> (32 - (r))); x1 ^= x0; }

__host__ __device__ static inline void tf2x32(uint32_t k0, uint32_t k1,
                                              uint32_t& x0, uint32_t& x1) {
  uint32_t ks2 = k0 ^ k1 ^ 0x1BD11BDAu;
  x0 += k0; x1 += k1;
  TF_ROUND(13) TF_ROUND(15) TF_ROUND(26) TF_ROUND(6)
  x0 += k1;  x1 += ks2 + 1u;
  TF_ROUND(17) TF_ROUND(29) TF_ROUND(16) TF_ROUND(24)
  x0 += ks2; x1 += k0 + 2u;
  TF_ROUND(13) TF_ROUND(15) TF_ROUND(26) TF_ROUND(6)
  x0 += k0;  x1 += k1 + 3u;
  TF_ROUND(17) TF_ROUND(29) TF_ROUND(16) TF_ROUND(24)
  x0 += k1;  x1 += ks2 + 4u;
  TF_ROUND(13) TF_ROUND(15) TF_ROUND(26) TF_ROUND(6)
  x0 += ks2; x1 += k0 + 5u;
}

// tight device hash with pre-baked key schedule; rotates via v_alignbit_b32
#define ROTL(x, r) __builtin_amdgcn_alignbit((x), (x), 32u - (r))
#define R4(a,b,c,d) { x0+=x1; x1=ROTL(x1,a); x1^=x0; \
                      x0+=x1; x1=ROTL(x1,b); x1^=x0; \
                      x0+=x1; x1=ROTL(x1,c); x1^=x0; \
                      x0+=x1; x1=ROTL(x1,d); x1^=x0; }

struct TFC { uint32_t x0i, sk1, a1,b1,a2,b2,a3,b3,a4,b4,a5,b5; };

__device__ static inline uint32_t tf_hash(uint32_t s, const TFC& c) {
  uint32_t x0 = c.x0i, x1 = s + c.sk1;
  R4(13,15,26,6)   x0 += c.a1; x1 += c.b1;
  R4(17,29,16,24)  x0 += c.a2; x1 += c.b2;
  R4(13,15,26,6)   x0 += c.a3; x1 += c.b3;
  R4(17,29,16,24)  x0 += c.a4; x1 += c.b4;
  R4(13,15,26,6)   x0 += c.a5; x1 += c.b5;
  return x0 ^ x1;
}

__device__ static inline unsigned long long shfl_down_u64(unsigned long long v, int off) {
  uint32_t lo = (uint32_t)v, hi = (uint32_t)(v >> 32);
  lo = __shfl_down(lo, off);
  hi = __shfl_down(hi, off);
  return ((unsigned long long)hi << 32) | lo;
}

// ---------------------------------------------------------------------------
// Kernel 1: compaction with per-block aggregation.
// 1024 blocks per batch (exactly); b uniform per block.
// ---------------------------------------------------------------------------
__global__ __launch_bounds__(256) void k_compact(const int* __restrict__ mask,
                                                 int* __restrict__ ctr,
                                                 uint32_t* __restrict__ lists) {
  int t = blockIdx.x * 256 + threadIdx.x;           // [0, 2*S_VOL)
  int b = blockIdx.x >> 10;
  int s = t & (S_VOL - 1);
  int z = s >> 12, y = (s >> 6) & 63, x = s & 63;
  int m = mask[t];
  int cnt = 0;
  #pragma unroll
  for (int dz = -1; dz <= 1; ++dz) {
    int zz = z + dz; if (zz < 0 || zz > 63) continue;
    #pragma unroll
    for (int dy = -1; dy <= 1; ++dy) {
      int yy = y + dy; if (yy < 0 || yy > 63) continue;
      #pragma unroll
      for (int dx = -1; dx <= 1; ++dx) {
        int xx = x + dx; if (xx < 0 || xx > 63) continue;
        cnt += mask[(b << 18) + (zz << 12) + (yy << 6) + xx];
      }
    }
  }
  bool pred[4];
  pred[1] = (m == 1);                 // pos
  pred[3] = (m == 0);                 // neg
  pred[0] = pred[1] && (cnt < 27);    // posb
  pred[2] = pred[3] && (cnt > 0);     // negb

  __shared__ int wcnt[4][4];          // [set][wave]
  __shared__ int wbase[4][4];
  int wave = threadIdx.x >> 6;
  int lane = threadIdx.x & 63;
  unsigned long long below = (lane == 63) ? ~0ull : ((1ull << (lane + 1)) - 1ull);
  below >>= 1;                        // bits strictly below lane

  int pre[4];
  #pragma unroll
  for (int set = 0; set < 4; ++set) {
    unsigned long long bv = __ballot(pred[set]);
    if (lane == 0) wcnt[set][wave] = (int)__popcll(bv);
    pre[set] = (int)__popcll(bv & below);
  }
  __syncthreads();
  if (threadIdx.x < 4) {
    int set = threadIdx.x;
    int c0 = wcnt[set][0], c1 = wcnt[set][1], c2 = wcnt[set][2], c3 = wcnt[set][3];
    int tot = c0 + c1 + c2 + c3;
    int base = 0;
    if (tot) base = atomicAdd(&ctr[CTR(b, set)], tot);
    wbase[set][0] = base;
    wbase[set][1] = base + c0;
    wbase[set][2] = base + c0 + c1;
    wbase[set][3] = base + c0 + c1 + c2;
  }
  __syncthreads();

  uint32_t* regA = lists + (size_t)b * (2 * S_VOL);
  uint32_t* regB = regA + S_VOL;
  #pragma unroll
  for (int set = 0; set < 4; ++set) {
    if (pred[set]) {
      int idx = wbase[set][wave] + pre[set];
      uint32_t* reg = (set & 1) ? regB : regA;
      reg[(set < 2) ? idx : (S_VOL - 1 - idx)] = (uint32_t)s;
    }
  }
}

// pad lists to uint4 alignment with duplicate entries (dups can't change max)
__global__ void k_pad(const int* __restrict__ ctr, uint32_t* __restrict__ lists) {
  int i = threadIdx.x;
  if (i >= 8) return;
  int b = i >> 2, set = i & 3;
  uint32_t* regA = lists + (size_t)b * (2 * S_VOL);
  uint32_t* reg = (set & 1) ? regA + S_VOL : regA;
  int cnt = ctr[CTR(b, set)];
  if (cnt == 0 || cnt == S_VOL) return;
  if (set < 2) {                 // front list: pad tail [cnt, roundup4)
    uint32_t v = reg[0];
    for (int q = cnt; q < ((cnt + 3) & ~3); ++q) reg[q] = v;
  } else {                       // back list: pad head [(S-cnt)&~3, S-cnt)
    int st = S_VOL - cnt;
    uint32_t v = reg[st];
    for (int q = (st & ~3); q < st; ++q) reg[q] = v;
  }
}

// ---------------------------------------------------------------------------
// Kernel 2: sampler. One wg per (slot d, chunk); 2048 wgs.
// ---------------------------------------------------------------------------
__global__ __launch_bounds__(256) void k_sample_list(const int* __restrict__ ctr,
                                                     const uint32_t* __restrict__ lists,
                                                     unsigned long long* __restrict__ slots,
                                                     Keys keys) {
  int wg = blockIdx.x;
  int chunk = wg & 1;
  int d = wg >> 1;                       // slot id in [0,1024)
  int c, rem;
  if      (d < 352) { c = 0; rem = d; }
  else if (d < 512) { c = 1; rem = d - 352; }
  else if (d < 864) { c = 2; rem = d - 512; }
  else              { c = 3; rem = d - 864; }
  int n = rem & 15, j = rem >> 4;
  int b = n >> 3;

  // mode: 0=list, 2=valid-arith, 3=all-arith
  int mode = 0, set = 0;
  if (c == 0)      { if (ctr[CTR(b,0)]) set = 0; else if (ctr[CTR(b,1)]) set = 1; else mode = 3; }
  else if (c == 1) { if (ctr[CTR(b,1)]) set = 1; else mode = 2; }
  else if (c == 2) { if (ctr[CTR(b,2)]) set = 2; else if (ctr[CTR(b,3)]) set = 3; else mode = 3; }
  else             { if (ctr[CTR(b,3)]) set = 3; else mode = 2; }

  uint32_t k0 = keys.k[c][0], k1 = keys.k[c][1];
  uint32_t ks2 = k0 ^ k1 ^ 0x1BD11BDAu;
  uint32_t ibase = (uint32_t)(j * 16 + n) * (uint32_t)S_VOL;
  TFC tc;
  tc.x0i = k0; tc.sk1 = ibase + k1;
  tc.a1 = k1;  tc.b1 = ks2 + 1u;
  tc.a2 = ks2; tc.b2 = k0 + 2u;
  tc.a3 = k0;  tc.b3 = k1 + 3u;
  tc.a4 = k1;  tc.b4 = ks2 + 4u;
  tc.a5 = ks2; tc.b5 = k0 + 5u;

  int tid = threadIdx.x;
  unsigned long long best = 0ull;

  if (mode == 0) {
    const uint32_t* regA = lists + (size_t)b * (2 * S_VOL);
    const uint32_t* reg = (set & 1) ? regA + S_VOL : regA;
    int cnt = ctr[CTR(b, set)];
    const uint32_t* base;
    int len4;
    if (set < 2) { base = reg; len4 = (cnt + 3) >> 2; }
    else { int st = (S_VOL - cnt) & ~3; base = reg + st; len4 = (S_VOL - st) >> 2; }
    const uint4* p4 = (const uint4*)base;
    for (uint32_t gi = (uint32_t)chunk; gi * 256u < (uint32_t)len4; gi += 2u) {
      uint32_t qi = gi * 256u + (uint32_t)tid;
      if (qi < (uint32_t)len4) {
        uint4 sv = p4[qi];
        #pragma unroll
        for (int u = 0; u < 4; ++u) {
          uint32_t s = (u == 0) ? sv.x : (u == 1) ? sv.y : (u == 2) ? sv.z : sv.w;
          uint32_t bits = tf_hash(s, tc);
          uint32_t vp = (bits >> 9) + 1u;
          unsigned long long key =
              ((unsigned long long)vp << 18) | (unsigned long long)((S_VOL - 1u) - s);
          best = best > key ? best : key;
        }
      }
    }
  } else if (mode == 2) {
    for (uint32_t i = (uint32_t)(chunk * 256 + tid); i < VALID_N; i += 512u) {
      uint32_t z = i / 3844u;
      uint32_t r2 = i - z * 3844u;
      uint32_t y = r2 / 62u;
      uint32_t x = r2 - y * 62u;
      uint32_t s = ((z + 1u) << 12) | ((y + 1u) << 6) | (x + 1u);
      uint32_t bits = tf_hash(s, tc);
      uint32_t vp = (bits >> 9) + 1u;
      unsigned long long key =
          ((unsigned long long)vp << 18) | (unsigned long long)((S_VOL - 1u) - s);
      best = best > key ? best : key;
    }
  } else {
    for (uint32_t s = (uint32_t)(chunk * 256 + tid); s < S_VOL; s += 512u) {
      uint32_t bits = tf_hash(s, tc);
      uint32_t vp = (bits >> 9) + 1u;
      unsigned long long key =
          ((unsigned long long)vp << 18) | (unsigned long long)((S_VOL - 1u) - s);
      best = best > key ? best : key;
    }
  }

  #pragma unroll
  for (int off = 32; off; off >>= 1) {
    unsigned long long o = shfl_down_u64(best, off);
    best = best > o ? best : o;
  }
  if ((tid & 63) == 0) atomicMax(&slots[d], best);
}

// ---------------------------------------------------------------------------
// Kernel 3: gather 3x3x3 patches (replicate pad == clamp).
// ---------------------------------------------------------------------------
__global__ __launch_bounds__(256) void k_gather(const float* __restrict__ fmap,
                                                const unsigned long long* __restrict__ slots,
                                                float* __restrict__ out) {
  int tid = blockIdx.x * 256 + threadIdx.x;
  if (tid >= OUT_N) return;
  int o  = tid % 27;
  int q  = tid / 27;
  int cg = q & 7;   q >>= 3;
  int m  = q & 31;  q >>= 5;
  int t  = q & 1;   q >>= 1;
  int gi = q & 7;
  int b  = q >> 3;
  int n  = b * 8 + gi;
  int slot;
  if (t == 0) slot = (m < 22) ? (m * 16 + n) : (352 + (m - 22) * 16 + n);
  else        slot = (m < 22) ? (512 + m * 16 + n) : (864 + (m - 22) * 16 + n);
  int s = (S_VOL - 1) - (int)(slots[slot] & 0x3FFFFull);
  int z = s >> 12, y = (s >> 6) & 63, x = s & 63;
  int dz = o / 9 - 1, dy = (o / 3) % 3 - 1, dx = o % 3 - 1;
  int zc = min(max(z + dz, 0), 63);
  int yc = min(max(y + dy, 0), 63);
  int xc = min(max(x + dx, 0), 63);
  int ch = gi * 8 + cg;
  out[tid] = fmap[((b * 64 + ch) << 18) + (zc << 12) + (yc << 6) + xc];
}

// ===========================================================================
extern "C" void kernel_launch(void* const* d_in, const int* in_sizes, int n_in,
                              void* d_out, int out_size, void* d_ws, size_t ws_size,
                              hipStream_t stream) {
  const float* fmap = (const float*)d_in[0];
  const int*   mask = (const int*)d_in[1];
  float* out = (float*)d_out;

  int* ctr = (int*)d_ws;                                                 // 8 × 64B
  unsigned long long* slots = (unsigned long long*)((char*)d_ws + 1024); // 1024 u64
  uint32_t* lists = (uint32_t*)((char*)d_ws + 16384);                    // 4*S u32

  // keys = jax.random.split(jax.random.key(42), 4): foldlike, RAW pair output
  Keys K;
  for (int c = 0; c < 4; ++c) {
    uint32_t x0 = 0u, x1 = (uint32_t)c;
    tf2x32(0u, 42u, x0, x1);
    K.k[c][0] = x0; K.k[c][1] = x1;
  }

  hipMemsetAsync(d_ws, 0, 16384, stream);
  hipLaunchKernelGGL(k_compact, dim3(2048), dim3(256), 0, stream, mask, ctr, lists);
  hipLaunchKernelGGL(k_pad, dim3(1), dim3(64), 0, stream, ctr, lists);
  hipLaunchKernelGGL(k_sample_list, dim3(2048), dim3(256), 0, stream, ctr, lists, slots, K);
  hipLaunchKernelGGL(k_gather, dim3((OUT_N + 255) / 256), dim3(256), 0, stream, fmap, slots, out);
}